// Round 10
// baseline (16980.849 us; speedup 1.0000x reference)
//
#include <hip/hip_runtime.h>
#include <hip/hip_bf16.h>

typedef __hip_bfloat16 bf16;
typedef __bf16 bf16x8_t __attribute__((ext_vector_type(8)));
typedef float f32x4_t __attribute__((ext_vector_type(4)));
typedef unsigned short u16x8_t __attribute__((ext_vector_type(8)));

#define HID 3584
#define SEQ 2048
#define NBATCH 2
#define MTOK 4096
#define NHEADS 16
#define NKVH 8
#define HDIM 256
#define QOUT 4096
#define KOUT 2048
#define INTERD 14336
#define EPSF 1e-6f

static __device__ __forceinline__ unsigned short f2bu(float f) {
  union { bf16 b; unsigned short u; } cv;
  cv.b = __float2bfloat16(f);
  return cv.u;
}

static __device__ __forceinline__ f32x4_t mfma16(bf16x8_t a, bf16x8_t b, f32x4_t c) {
  return __builtin_amdgcn_mfma_f32_16x16x32_bf16(a, b, c, 0, 0, 0);
}

static __device__ __forceinline__ void gl_lds16(const void* g, void* l) {
  __builtin_amdgcn_global_load_lds((__attribute__((address_space(1))) void*)g,
                                   (__attribute__((address_space(3))) void*)l,
                                   16, 0, 0);
}

static __device__ __forceinline__ float block_reduce_sum(float v) {
  __shared__ float buf[4];
  #pragma unroll
  for (int m = 1; m < 64; m <<= 1) v += __shfl_xor(v, m, 64);
  __syncthreads();
  if ((threadIdx.x & 63) == 0) buf[threadIdx.x >> 6] = v;
  __syncthreads();
  return buf[0] + buf[1] + buf[2] + buf[3];
}

// ---------------------------------------------------------------------------
// weight convert: f32 -> bf16
// ---------------------------------------------------------------------------
__global__ __launch_bounds__(256) void cvt_w(
    const float* __restrict__ src, bf16* __restrict__ dst, int n) {
  const int stride = gridDim.x * 256 * 8;
  for (int i = (blockIdx.x * 256 + threadIdx.x) * 8; i < n; i += stride) {
    const float4 a = *(const float4*)(src + i);
    const float4 b = *(const float4*)(src + i + 4);
    u16x8_t o;
    o[0] = f2bu(a.x); o[1] = f2bu(a.y); o[2] = f2bu(a.z); o[3] = f2bu(a.w);
    o[4] = f2bu(b.x); o[5] = f2bu(b.y); o[6] = f2bu(b.z); o[7] = f2bu(b.w);
    *(u16x8_t*)(dst + i) = o;
  }
}

// ---------------------------------------------------------------------------
// 256x256 GEMM, BK=32, double-buffered LDS = 64 KiB -> 2 BLOCKS/CU.
// R10: R9 ablation showed MFMA/LDS-read/staging fully SERIALIZE at 1 block/CU
// (FULL = sum of parts; 7800 cyc/tile vs 2480 MFMA floor). m97/m114: overlap
// comes from independent blocks per CU. Halving BK halves LDS -> 2 co-resident
// blocks with independent barriers overlap each other's phases.
// LDS layout per op-tile [256 rows][32 k] bf16, 64B rows, chunk-swizzled:
//   LDS[row][chunk] holds global k-chunk (chunk ^ ((row>>1)&3)) (involution).
//   Read: chunk' = lg ^ ((lr>>1)&3) -> 8 lanes per 4-bank group (optimal).
// vmcnt: 4 loads/tile; entry/tail vmcnt(4); tail vmcnt(0) when T+2>=NT.
// ---------------------------------------------------------------------------
enum { EPI_BF16 = 0, EPI_F32 = 1, EPI_GELUMUL = 2, EPI_QK = 3, EPI_VSW = 4 };

template <int EPI>
__global__ __launch_bounds__(512, 4) void gemm8p(
    const bf16* __restrict__ A, const bf16* __restrict__ Bw,
    void* __restrict__ Cout, const bf16* __restrict__ aux,
    void* __restrict__ C2, int Ndim, int Kdim, int mshift) {
  __shared__ __align__(16) char L[65536];  // [buf2][op2][row256][k32] bf16

  const int NT = Kdim >> 5;
  const int NB = gridDim.x;
  const int bid = blockIdx.x;
  const int sw = (bid & 7) * (NB >> 3) + (bid >> 3);
  const int m0 = (sw & ((1 << mshift) - 1)) << 8;
  const int n0 = (sw >> mshift) << 8;

  const int tid = threadIdx.x;
  const int wid = tid >> 6, l = tid & 63;
  const int wm = wid >> 2, wn = wid & 3;
  const int lr = l & 15, lg = l >> 4;

  // --- staging geometry: thread t -> row = wid*16 + (l>>2) (+128 for load 1),
  // global col elems = ((l&3) ^ ((l>>3)&3)) * 8 (inverse swizzle, lane-pure).
  const int rlane = wid * 16 + (l >> 2);
  const int lc8 = (((l & 3) ^ ((l >> 3) & 3)) << 3);
  const bf16* srcA = A + (size_t)(m0 + rlane) * Kdim + lc8;
  const bf16* srcB = Bw + (size_t)(n0 + rlane) * Kdim + lc8;
  const size_t K128 = (size_t)Kdim << 7;  // 128 rows of elems

  auto STAGE2 = [&](int op, int tl) {  // one op (A or B), one tile: 2 loads
    if (tl >= NT) return;
    const bf16* s = (op ? srcB : srcA) + ((size_t)tl << 5);
    char* d = L + ((tl & 1) << 15) + (op << 14) + (wid << 10);
    gl_lds16(s, d);
    gl_lds16(s + K128, d + 8192);
  };

  // --- fragment read geometry (swizzled chunk) ---
  const int arow = wm * 128 + lr;
  const int brow = wn * 64 + lr;
  const int ch = (lg ^ ((lr >> 1) & 3)) << 4;  // byte offset of 16B chunk
  auto LDA = [&](int mi, int c) {
    return *(const bf16x8_t*)(L + (c << 15) + arow * 64 + mi * 1024 + ch);
  };
  auto LDB = [&](int ni, int c) {
    return *(const bf16x8_t*)(L + (c << 15) + 16384 + brow * 64 + ni * 1024 + ch);
  };

  f32x4_t acc[8][4];
  #pragma unroll
  for (int i = 0; i < 8; i++)
    #pragma unroll
    for (int j = 0; j < 4; j++) acc[i][j] = (f32x4_t){0.f, 0.f, 0.f, 0.f};

  bf16x8_t fa[8], fb[4];

  // prologue: tiles 0 and 1 (8 loads). vmcnt(4) -> tile 0's 4 loads done.
  STAGE2(1, 0); STAGE2(0, 0); STAGE2(1, 1); STAGE2(0, 1);
  asm volatile("s_waitcnt vmcnt(4)" ::: "memory");

#define MFMA_Q(MB, NBQ)                                                        \
  _Pragma("unroll") for (int mi = 0; mi < 4; ++mi)                             \
  _Pragma("unroll") for (int ni = 0; ni < 2; ++ni) {                           \
    acc[MB + mi][NBQ + ni] =                                                   \
        mfma16(fa[MB + mi], fb[NBQ + ni], acc[MB + mi][NBQ + ni]);             \
  }

#define TILE(T, C)                                                             \
  {                                                                            \
    /* ph0: publish barrier; reads fa0-3, fb0-1; MFMA Q(0,0) */                \
    __builtin_amdgcn_s_barrier();                                              \
    _Pragma("unroll") for (int mi = 0; mi < 4; ++mi) fa[mi] = LDA(mi, (C));    \
    _Pragma("unroll") for (int ni = 0; ni < 2; ++ni) fb[ni] = LDB(ni, (C));    \
    asm volatile("s_waitcnt lgkmcnt(0)" ::: "memory");                         \
    __builtin_amdgcn_s_setprio(1);                                             \
    MFMA_Q(0, 0);                                                              \
    __builtin_amdgcn_s_setprio(0);                                             \
    /* ph1: reads fb2-3 pre-barrier; MFMA Q(0,2) */                            \
    _Pragma("unroll") for (int ni = 2; ni < 4; ++ni) fb[ni] = LDB(ni, (C));    \
    __builtin_amdgcn_s_barrier();                                              \
    asm volatile("s_waitcnt lgkmcnt(0)" ::: "memory");                         \
    __builtin_amdgcn_s_setprio(1);                                             \
    MFMA_Q(0, 2);                                                              \
    __builtin_amdgcn_s_setprio(0);                                             \
    /* ph2: reads fa4-7 pre-barrier; stage B(T+2); MFMA Q(4,0) */              \
    _Pragma("unroll") for (int mi = 4; mi < 8; ++mi) fa[mi] = LDA(mi, (C));    \
    __builtin_amdgcn_s_barrier();                                              \
    asm volatile("s_waitcnt lgkmcnt(0)" ::: "memory");                         \
    STAGE2(1, (T) + 2);                                                        \
    __builtin_amdgcn_s_setprio(1);                                             \
    MFMA_Q(4, 0);                                                              \
    __builtin_amdgcn_s_setprio(0);                                             \
    /* ph3: barrier; stage A(T+2); MFMA Q(4,2); tail-aware vmcnt */            \
    __builtin_amdgcn_s_barrier();                                              \
    STAGE2(0, (T) + 2);                                                        \
    __builtin_amdgcn_s_setprio(1);                                             \
    MFMA_Q(4, 2);                                                              \
    __builtin_amdgcn_s_setprio(0);                                             \
    if ((T) + 2 < NT) {                                                        \
      asm volatile("s_waitcnt vmcnt(4)" ::: "memory");                         \
    } else {                                                                   \
      asm volatile("s_waitcnt vmcnt(0)" ::: "memory");                         \
    }                                                                          \
  }

  for (int t = 0; t < NT; t += 2) {
    TILE(t, 0);
    TILE(t + 1, 1);
  }
#undef TILE
#undef MFMA_Q

  // Epilogue. C/D layout: col = lane&15, row = (lane>>4)*4 + reg.
  const int row0 = m0 + wm * 128 + lg * 4;
  const int col0 = n0 + wn * 64 + lr;
  #pragma unroll
  for (int mi = 0; mi < 8; mi++) {
    #pragma unroll
    for (int ni = 0; ni < 4; ni++) {
      #pragma unroll
      for (int r = 0; r < 4; r++) {
        const int row = row0 + mi * 16 + r;
        const int col = col0 + ni * 16;
        const float v = acc[mi][ni][r];
        if constexpr (EPI == EPI_BF16) {
          ((bf16*)Cout)[(size_t)row * Ndim + col] = __float2bfloat16(v);
        } else if constexpr (EPI == EPI_F32) {
          ((float*)Cout)[(size_t)row * Ndim + col] = v;
        } else if constexpr (EPI == EPI_QK) {
          if (col < 4096) {
            ((bf16*)Cout)[(size_t)row * 4096 + col] = __float2bfloat16(v);
          } else {
            ((bf16*)C2)[(size_t)row * 2048 + (col - 4096)] =
                __float2bfloat16(v);
          }
        } else if constexpr (EPI == EPI_VSW) {
          const int bb = col >> 11, s = col & 2047;
          ((bf16*)Cout)[(((size_t)((bb * 8 + (row >> 8)) * 256 + (row & 255)))
                         << 11) + s] = __float2bfloat16(v);
        } else {  // EPI_GELUMUL
          const float g = __bfloat162float(aux[(size_t)row * Ndim + col]);
          const float u = 0.7978845608028654f * (g + 0.044715f * g * g * g);
          const float gl = 0.5f * g * (1.f + tanhf(u));
          ((bf16*)Cout)[(size_t)row * Ndim + col] = __float2bfloat16(gl * v);
        }
      }
    }
  }
  (void)aux; (void)C2;
}

// ---------------------------------------------------------------------------
// RMSNorm of input hidden -> bf16
// ---------------------------------------------------------------------------
__global__ __launch_bounds__(256) void rmsnorm_in(
    const float* __restrict__ x, const float* __restrict__ w,
    bf16* __restrict__ out) {
  const int row = blockIdx.x, t = threadIdx.x;
  const float4* xr = (const float4*)(x + (size_t)row * HID);
  float4 v[4];
  float ss = 0.f;
  #pragma unroll
  for (int j = 0; j < 4; j++) {
    const int idx = t + 256 * j;
    if (idx < HID / 4) {
      v[j] = xr[idx];
      ss += v[j].x * v[j].x + v[j].y * v[j].y + v[j].z * v[j].z + v[j].w * v[j].w;
    }
  }
  ss = block_reduce_sum(ss);
  const float sc = rsqrtf(ss * (1.f / HID) + EPSF);
  const float4* w4 = (const float4*)w;
  bf16* orow = out + (size_t)row * HID;
  #pragma unroll
  for (int j = 0; j < 4; j++) {
    const int idx = t + 256 * j;
    if (idx < HID / 4) {
      const float4 wv = w4[idx];
      ushort4 o;
      o.x = f2bu(v[j].x * sc * (1.f + wv.x));
      o.y = f2bu(v[j].y * sc * (1.f + wv.y));
      o.z = f2bu(v[j].z * sc * (1.f + wv.z));
      o.w = f2bu(v[j].w * sc * (1.f + wv.w));
      *(ushort4*)(orow + idx * 4) = o;
    }
  }
}

// ---------------------------------------------------------------------------
// RoPE in-place on q (16 heads) and k (8 heads), bf16.
// ---------------------------------------------------------------------------
__global__ __launch_bounds__(128) void rope_kernel(
    bf16* __restrict__ q, bf16* __restrict__ k,
    const float* __restrict__ cosb, const float* __restrict__ sinb) {
  const int tok = blockIdx.x;
  const int hs = blockIdx.y;
  const int d = threadIdx.x;
  const int s = tok & (SEQ - 1);
  bf16* ptr = (hs < NHEADS)
                  ? q + (size_t)tok * QOUT + hs * HDIM
                  : k + (size_t)tok * KOUT + (hs - NHEADS) * HDIM;
  const float c = cosb[s * HDIM + d];
  const float sn = sinb[s * HDIM + d];
  const float x0 = __bfloat162float(ptr[d]);
  const float x1 = __bfloat162float(ptr[d + 128]);
  ptr[d] = __float2bfloat16(x0 * c - x1 * sn);
  ptr[d + 128] = __float2bfloat16(x1 * c + x0 * sn);
}

// ---------------------------------------------------------------------------
// Flash attention, sliding window 1024, softcap 50, fixed-base softmax.
// ---------------------------------------------------------------------------
__global__ __launch_bounds__(256) void attn_kernel(
    const bf16* __restrict__ q, const bf16* __restrict__ k,
    const bf16* __restrict__ vt, bf16* __restrict__ out) {
  __shared__ __align__(16) bf16 plds[4][16 * 32];

  const int qt = blockIdx.x, h = blockIdx.y, b = blockIdx.z;
  const int w = threadIdx.x >> 6, l = threadIdx.x & 63;
  const int kvh = h >> 1;
  const int qbase = qt * 64 + w * 16;
  const int lr = l & 15, lg = l >> 4, lk = lg * 8;

  bf16x8_t qf[8];
  const bf16* qrow = q + (size_t)(b * SEQ + qbase + lr) * QOUT + h * HDIM;
  #pragma unroll
  for (int c = 0; c < 8; c++) qf[c] = *(const bf16x8_t*)(qrow + c * 32 + lk);

  f32x4_t acc[16];
  #pragma unroll
  for (int i = 0; i < 16; i++) acc[i] = (f32x4_t){0.f, 0.f, 0.f, 0.f};
  float L[4] = {0.f, 0.f, 0.f, 0.f};

  const bf16* kp = k + (size_t)(b * SEQ) * KOUT + kvh * HDIM;
  const bf16* vp = vt + (size_t)(b * NKVH + kvh) * HDIM * SEQ;
  bf16* pl = &plds[w][0];

  int kstart = qbase - 1023;
  if (kstart < 0) kstart = 0;
  kstart &= ~31;
  const int kend = qbase + 15;

  for (int kb = kstart; kb <= kend; kb += 32) {
    f32x4_t s0 = (f32x4_t){0.f, 0.f, 0.f, 0.f};
    f32x4_t s1 = (f32x4_t){0.f, 0.f, 0.f, 0.f};
    #pragma unroll
    for (int c = 0; c < 8; c++) {
      bf16x8_t k0 = *(const bf16x8_t*)(kp + (size_t)(kb + lr) * KOUT + c * 32 + lk);
      bf16x8_t k1 = *(const bf16x8_t*)(kp + (size_t)(kb + 16 + lr) * KOUT + c * 32 + lk);
      s0 = mfma16(qf[c], k0, s0);
      s1 = mfma16(qf[c], k1, s1);
    }
    float p[8];
    #pragma unroll
    for (int sub = 0; sub < 2; sub++) {
      const int j = kb + sub * 16 + lr;
      #pragma unroll
      for (int r = 0; r < 4; r++) {
        const int i = qbase + lg * 4 + r;
        float sc = (sub ? s1[r] : s0[r]) * 0.0625f;
        sc = 50.f * tanhf(sc * 0.02f);
        const bool ok = (j <= i) && (j > i - 1024);
        p[sub * 4 + r] = ok ? __expf(sc) : 0.f;
      }
    }
    #pragma unroll
    for (int r = 0; r < 4; r++) {
      float ps = p[r] + p[4 + r];
      ps += __shfl_xor(ps, 1, 64);
      ps += __shfl_xor(ps, 2, 64);
      ps += __shfl_xor(ps, 4, 64);
      ps += __shfl_xor(ps, 8, 64);
      L[r] += ps;
    }
    #pragma unroll
    for (int sub = 0; sub < 2; sub++)
      #pragma unroll
      for (int r = 0; r < 4; r++)
        pl[(lg * 4 + r) * 32 + sub * 16 + lr] = __float2bfloat16(p[sub * 4 + r]);
    asm volatile("s_waitcnt lgkmcnt(0)" ::: "memory");
    const bf16x8_t pa = *(const bf16x8_t*)(pl + lr * 32 + lk);
    #pragma unroll
    for (int dt = 0; dt < 16; dt++) {
      bf16x8_t bv = *(const bf16x8_t*)(vp + (size_t)(dt * 16 + lr) * SEQ + kb + lk);
      acc[dt] = mfma16(pa, bv, acc[dt]);
    }
  }

  float rL[4];
  #pragma unroll
  for (int r = 0; r < 4; r++) rL[r] = 1.f / L[r];
  #pragma unroll
  for (int dt = 0; dt < 16; dt++) {
    #pragma unroll
    for (int r = 0; r < 4; r++) {
      const int tok = b * SEQ + qbase + lg * 4 + r;
      out[(size_t)tok * QOUT + h * HDIM + dt * 16 + lr] =
          __float2bfloat16(acc[dt][r] * rL[r]);
    }
  }
}

// ---------------------------------------------------------------------------
// fuse1: h1 = hidden + rmsnorm(attn_proj, w_post); y = bf16(rmsnorm(h1, w_pre))
// ---------------------------------------------------------------------------
__global__ __launch_bounds__(256) void fuse_attn(
    const float* __restrict__ hidden, const float* __restrict__ ap,
    const float* __restrict__ w_post, const float* __restrict__ w_pre,
    float* __restrict__ h1, bf16* __restrict__ y) {
  const int row = blockIdx.x, t = threadIdx.x;
  const float4* ar = (const float4*)(ap + (size_t)row * HID);
  const float4* hr = (const float4*)(hidden + (size_t)row * HID);
  float4 a[4];
  float ss = 0.f;
  #pragma unroll
  for (int j = 0; j < 4; j++) {
    const int idx = t + 256 * j;
    if (idx < HID / 4) {
      a[j] = ar[idx];
      ss += a[j].x * a[j].x + a[j].y * a[j].y + a[j].z * a[j].z + a[j].w * a[j].w;
    }
  }
  ss = block_reduce_sum(ss);
  const float sc = rsqrtf(ss * (1.f / HID) + EPSF);
  const float4* wpo = (const float4*)w_post;
  float4* h1r = (float4*)(h1 + (size_t)row * HID);
  float4 hv[4];
  float ss2 = 0.f;
  #pragma unroll
  for (int j = 0; j < 4; j++) {
    const int idx = t + 256 * j;
    if (idx < HID / 4) {
      const float4 wv = wpo[idx];
      const float4 x = hr[idx];
      hv[j].x = x.x + a[j].x * sc * (1.f + wv.x);
      hv[j].y = x.y + a[j].y * sc * (1.f + wv.y);
      hv[j].z = x.z + a[j].z * sc * (1.f + wv.z);
      hv[j].w = x.w + a[j].w * sc * (1.f + wv.w);
      ss2 += hv[j].x * hv[j].x + hv[j].y * hv[j].y + hv[j].z * hv[j].z + hv[j].w * hv[j].w;
      h1r[idx] = hv[j];
    }
  }
  ss2 = block_reduce_sum(ss2);
  const float sc2 = rsqrtf(ss2 * (1.f / HID) + EPSF);
  const float4* wpr = (const float4*)w_pre;
  bf16* yr = y + (size_t)row * HID;
  #pragma unroll
  for (int j = 0; j < 4; j++) {
    const int idx = t + 256 * j;
    if (idx < HID / 4) {
      const float4 wv = wpr[idx];
      ushort4 o;
      o.x = f2bu(hv[j].x * sc2 * (1.f + wv.x));
      o.y = f2bu(hv[j].y * sc2 * (1.f + wv.y));
      o.z = f2bu(hv[j].z * sc2 * (1.f + wv.z));
      o.w = f2bu(hv[j].w * sc2 * (1.f + wv.w));
      *(ushort4*)(yr + idx * 4) = o;
    }
  }
}

// ---------------------------------------------------------------------------
// fuse2: out = h1 + rmsnorm(mlp, w_post_ff)
// ---------------------------------------------------------------------------
__global__ __launch_bounds__(256) void fuse_out(
    const float* __restrict__ h1, const float* __restrict__ mlp,
    const float* __restrict__ w, float* __restrict__ out) {
  const int row = blockIdx.x, t = threadIdx.x;
  const float4* mr = (const float4*)(mlp + (size_t)row * HID);
  float4 m[4];
  float ss = 0.f;
  #pragma unroll
  for (int j = 0; j < 4; j++) {
    const int idx = t + 256 * j;
    if (idx < HID / 4) {
      m[j] = mr[idx];
      ss += m[j].x * m[j].x + m[j].y * m[j].y + m[j].z * m[j].z + m[j].w * m[j].w;
    }
  }
  ss = block_reduce_sum(ss);
  const float sc = rsqrtf(ss * (1.f / HID) + EPSF);
  const float4* hr = (const float4*)(h1 + (size_t)row * HID);
  const float4* w4 = (const float4*)w;
  float4* orow = (float4*)(out + (size_t)row * HID);
  #pragma unroll
  for (int j = 0; j < 4; j++) {
    const int idx = t + 256 * j;
    if (idx < HID / 4) {
      const float4 wv = w4[idx];
      const float4 x = hr[idx];
      float4 o;
      o.x = x.x + m[j].x * sc * (1.f + wv.x);
      o.y = x.y + m[j].y * sc * (1.f + wv.y);
      o.z = x.z + m[j].z * sc * (1.f + wv.z);
      o.w = x.w + m[j].w * sc * (1.f + wv.w);
      orow[idx] = o;
    }
  }
}

// ---------------------------------------------------------------------------
extern "C" void kernel_launch(void* const* d_in, const int* in_sizes, int n_in,
                              void* d_out, int out_size, void* d_ws,
                              size_t ws_size, hipStream_t stream) {
  const float* hidden = (const float*)d_in[0];
  const float* cosb = (const float*)d_in[1];
  const float* sinb = (const float*)d_in[2];
  const float* Wq = (const float*)d_in[3];
  const float* Wk = (const float*)d_in[4];
  const float* Wv = (const float*)d_in[5];
  const float* Wo = (const float*)d_in[6];
  const float* Wgate = (const float*)d_in[7];
  const float* Wup = (const float*)d_in[8];
  const float* Wdown = (const float*)d_in[9];
  const float* w_in = (const float*)d_in[10];
  const float* w_post_attn = (const float*)d_in[11];
  const float* w_pre_ff = (const float*)d_in[12];
  const float* w_post_ff = (const float*)d_in[13];
  float* out = (float*)d_out;

  (void)in_sizes; (void)n_in; (void)out_size; (void)ws_size;

  const size_t WB = 102760448;  // 14336*3584*2 — bf16 weight scratch
  char* ws = (char*)d_ws;
  bf16* wbuf = (bf16*)ws;
  char* ab = ws + WB;

  bf16* xn = (bf16*)(ab);
  bf16* q = (bf16*)(ab + 29360128);
  float* attn_proj = (float*)(ab);
  float* mlp = (float*)(ab);
  bf16* kbuf = (bf16*)(ab + 62914560);
  bf16* vt = (bf16*)(ab + 62914560 + 16777216);
  bf16* attn_out = (bf16*)(ab + 62914560 + 33554432);
  float* h1 = (float*)(ab + 62914560);
  bf16* y = (bf16*)(ab + 130023424);
  bf16* gate = (bf16*)(ab + 159383552);

  rmsnorm_in<<<MTOK, 256, 0, stream>>>(hidden, w_in, xn);

  // wbuf rows [0,4096)=Wq, [4096,6144)=Wk, [6144,8192)=Wv
  cvt_w<<<4096, 256, 0, stream>>>(Wq, wbuf, QOUT * HID);
  cvt_w<<<2048, 256, 0, stream>>>(Wk, wbuf + (size_t)QOUT * HID, KOUT * HID);
  cvt_w<<<2048, 256, 0, stream>>>(Wv, wbuf + (size_t)(QOUT + KOUT) * HID,
                                  KOUT * HID);
  gemm8p<EPI_QK><<<(6144 / 256) * 16, 512, 0, stream>>>(
      xn, wbuf, q, nullptr, kbuf, 6144, HID, 4);
  gemm8p<EPI_VSW><<<(4096 / 256) * 8, 512, 0, stream>>>(
      wbuf + (size_t)(QOUT + KOUT) * HID, xn, vt, nullptr, nullptr,
      4096, HID, 3);
  rope_kernel<<<dim3(MTOK, NHEADS + NKVH), 128, 0, stream>>>(q, kbuf, cosb, sinb);
  attn_kernel<<<dim3(SEQ / 64, NHEADS, NBATCH), 256, 0, stream>>>(
      q, kbuf, vt, attn_out);
  cvt_w<<<4096, 256, 0, stream>>>(Wo, wbuf, HID * QOUT);
  gemm8p<EPI_F32><<<(HID / 256) * 16, 512, 0, stream>>>(
      attn_out, wbuf, attn_proj, nullptr, nullptr, HID, QOUT, 4);
  fuse_attn<<<MTOK, 256, 0, stream>>>(hidden, attn_proj, w_post_attn,
                                      w_pre_ff, h1, y);
  cvt_w<<<4096, 256, 0, stream>>>(Wgate, wbuf, INTERD * HID);
  gemm8p<EPI_BF16><<<(INTERD / 256) * 16, 512, 0, stream>>>(
      y, wbuf, gate, nullptr, nullptr, INTERD, HID, 4);
  cvt_w<<<4096, 256, 0, stream>>>(Wup, wbuf, INTERD * HID);
  gemm8p<EPI_GELUMUL><<<(INTERD / 256) * 16, 512, 0, stream>>>(
      y, wbuf, gate, gate, nullptr, INTERD, HID, 4);
  cvt_w<<<4096, 256, 0, stream>>>(Wdown, wbuf, INTERD * HID);
  gemm8p<EPI_F32><<<(HID / 256) * 16, 512, 0, stream>>>(
      gate, wbuf, mlp, nullptr, nullptr, HID, INTERD, 4);

  fuse_out<<<MTOK, 256, 0, stream>>>(h1, mlp, w_post_ff, out);
}

// Round 11
// 3218.093 us; speedup vs baseline: 5.2767x; 5.2767x over previous
//
#include <hip/hip_runtime.h>
#include <hip/hip_bf16.h>

typedef __hip_bfloat16 bf16;
typedef __bf16 bf16x8_t __attribute__((ext_vector_type(8)));
typedef float f32x4_t __attribute__((ext_vector_type(4)));
typedef unsigned short u16x8_t __attribute__((ext_vector_type(8)));

#define HID 3584
#define SEQ 2048
#define NBATCH 2
#define MTOK 4096
#define NHEADS 16
#define NKVH 8
#define HDIM 256
#define QOUT 4096
#define KOUT 2048
#define INTERD 14336
#define EPSF 1e-6f

static __device__ __forceinline__ unsigned short f2bu(float f) {
  union { bf16 b; unsigned short u; } cv;
  cv.b = __float2bfloat16(f);
  return cv.u;
}

static __device__ __forceinline__ f32x4_t mfma16(bf16x8_t a, bf16x8_t b, f32x4_t c) {
  return __builtin_amdgcn_mfma_f32_16x16x32_bf16(a, b, c, 0, 0, 0);
}

static __device__ __forceinline__ void gl_lds16(const void* g, void* l) {
  __builtin_amdgcn_global_load_lds((__attribute__((address_space(1))) void*)g,
                                   (__attribute__((address_space(3))) void*)l,
                                   16, 0, 0);
}

static __device__ __forceinline__ float block_reduce_sum(float v) {
  __shared__ float buf[4];
  #pragma unroll
  for (int m = 1; m < 64; m <<= 1) v += __shfl_xor(v, m, 64);
  __syncthreads();
  if ((threadIdx.x & 63) == 0) buf[threadIdx.x >> 6] = v;
  __syncthreads();
  return buf[0] + buf[1] + buf[2] + buf[3];
}

// ---------------------------------------------------------------------------
// weight convert: f32 -> bf16
// ---------------------------------------------------------------------------
__global__ __launch_bounds__(256) void cvt_w(
    const float* __restrict__ src, bf16* __restrict__ dst, int n) {
  const int stride = gridDim.x * 256 * 8;
  for (int i = (blockIdx.x * 256 + threadIdx.x) * 8; i < n; i += stride) {
    const float4 a = *(const float4*)(src + i);
    const float4 b = *(const float4*)(src + i + 4);
    u16x8_t o;
    o[0] = f2bu(a.x); o[1] = f2bu(a.y); o[2] = f2bu(a.z); o[3] = f2bu(a.w);
    o[4] = f2bu(b.x); o[5] = f2bu(b.y); o[6] = f2bu(b.z); o[7] = f2bu(b.w);
    *(u16x8_t*)(dst + i) = o;
  }
}

// ---------------------------------------------------------------------------
// 128x128 GEMM, 4 waves (2x2, per-wave 64x64), BK=32, dbuf LDS = 32 KiB.
// R11: R10's 2-block attempt spilled (acc alone = 128 regs > 128-reg budget).
// Shrink per-wave acc to 64 regs (64x64 output) so 3 blocks/CU fit at
// __launch_bounds__(256,3) (170-reg budget; est ~130 used). 3 independent
// blocks/CU = m97/m114's verified overlap regime: block A's MFMA overlaps
// block B's ds_reads/staging via the CU scheduler, no intra-block pipelining
// needed. 2 barriers + counted trailing vmcnt per K-tile.
// LDS [buf2][op2][row128][k32] bf16; 64B rows; chunk swizzle c^=(row>>1)&3
// (involution; consistent for all frag rows since offsets are 0 mod 8).
// vmcnt: 4 loads/tile; trailing vmcnt(4), tail-aware vmcnt(0).
// ---------------------------------------------------------------------------
enum { EPI_BF16 = 0, EPI_F32 = 1, EPI_GELUMUL = 2, EPI_QK = 3, EPI_VSW = 4 };

template <int EPI>
__global__ __launch_bounds__(256, 3) void gemm4w(
    const bf16* __restrict__ A, const bf16* __restrict__ Bw,
    void* __restrict__ Cout, const bf16* __restrict__ aux,
    void* __restrict__ C2, int Ndim, int Kdim, int mshift) {
  __shared__ __align__(16) char L[32768];

  const int NT = Kdim >> 5;
  const int NB = gridDim.x;
  const int bid = blockIdx.x;
  const int sw = (bid & 7) * (NB >> 3) + (bid >> 3);
  const int m0 = (sw & ((1 << mshift) - 1)) << 7;
  const int n0 = (sw >> mshift) << 7;

  const int tid = threadIdx.x;
  const int wid = tid >> 6, l = tid & 63;
  const int wm = wid >> 1, wn = wid & 1;
  const int lr = l & 15, lg = l >> 4;

  // staging: thread t -> row t>>2 (16B chunk t&3), source chunk inverse-swz.
  const int rl = tid >> 2;
  const int lc8 = (((l & 3) ^ ((l >> 3) & 3)) << 3);
  const bf16* srcA = A + (size_t)(m0 + rl) * Kdim + lc8;
  const bf16* srcB = Bw + (size_t)(n0 + rl) * Kdim + lc8;
  const size_t K64 = (size_t)Kdim << 6;  // 64 rows of elems

  auto STAGE2 = [&](int op, int tl) {  // one op (A or B), one tile: 2 loads
    if (tl >= NT) return;
    const bf16* s = (op ? srcB : srcA) + ((size_t)tl << 5);
    char* d = L + ((tl & 1) << 14) + (op << 13) + (wid << 10);
    gl_lds16(s, d);
    gl_lds16(s + K64, d + 4096);
  };

  // fragment reads (swizzled chunk)
  const int arow = wm * 64 + lr;
  const int brow = wn * 64 + lr;
  const int ch = (lg ^ ((lr >> 1) & 3)) << 4;
  auto LDA = [&](int mi, int c) {
    return *(const bf16x8_t*)(L + (c << 14) + (arow + mi * 16) * 64 + ch);
  };
  auto LDB = [&](int ni, int c) {
    return *(const bf16x8_t*)(L + (c << 14) + 8192 + (brow + ni * 16) * 64 + ch);
  };

  f32x4_t acc[4][4];
  #pragma unroll
  for (int i = 0; i < 4; i++)
    #pragma unroll
    for (int j = 0; j < 4; j++) acc[i][j] = (f32x4_t){0.f, 0.f, 0.f, 0.f};

  bf16x8_t fa[4], fb[4];

  // prologue: tiles 0 and 1 (8 loads); vmcnt(4) -> tile 0's 4 loads landed.
  STAGE2(1, 0); STAGE2(0, 0); STAGE2(1, 1); STAGE2(0, 1);
  asm volatile("s_waitcnt vmcnt(4)" ::: "memory");

#define TILE(T, C)                                                             \
  {                                                                            \
    __builtin_amdgcn_s_barrier(); /* publish tile T */                         \
    _Pragma("unroll") for (int mi = 0; mi < 4; ++mi) fa[mi] = LDA(mi, (C));    \
    _Pragma("unroll") for (int ni = 0; ni < 4; ++ni) fb[ni] = LDB(ni, (C));    \
    asm volatile("s_waitcnt lgkmcnt(0)" ::: "memory");                         \
    __builtin_amdgcn_s_barrier(); /* all waves' reads of buf C done */         \
    STAGE2(1, (T) + 2);                                                        \
    STAGE2(0, (T) + 2);                                                        \
    __builtin_amdgcn_s_setprio(1);                                             \
    _Pragma("unroll") for (int mi = 0; mi < 4; ++mi)                           \
    _Pragma("unroll") for (int ni = 0; ni < 4; ++ni)                           \
      acc[mi][ni] = mfma16(fa[mi], fb[ni], acc[mi][ni]);                       \
    __builtin_amdgcn_s_setprio(0);                                             \
    if ((T) + 2 < NT) {                                                        \
      asm volatile("s_waitcnt vmcnt(4)" ::: "memory");                         \
    } else {                                                                   \
      asm volatile("s_waitcnt vmcnt(0)" ::: "memory");                         \
    }                                                                          \
  }

  for (int t = 0; t < NT; t += 2) {
    TILE(t, 0);
    TILE(t + 1, 1);
  }
#undef TILE

  // Epilogue. C/D layout: col = lane&15, row = (lane>>4)*4 + reg.
  const int row0 = m0 + wm * 64 + lg * 4;
  const int col0 = n0 + wn * 64 + lr;
  #pragma unroll
  for (int mi = 0; mi < 4; mi++) {
    #pragma unroll
    for (int ni = 0; ni < 4; ni++) {
      #pragma unroll
      for (int r = 0; r < 4; r++) {
        const int row = row0 + mi * 16 + r;
        const int col = col0 + ni * 16;
        const float v = acc[mi][ni][r];
        if constexpr (EPI == EPI_BF16) {
          ((bf16*)Cout)[(size_t)row * Ndim + col] = __float2bfloat16(v);
        } else if constexpr (EPI == EPI_F32) {
          ((float*)Cout)[(size_t)row * Ndim + col] = v;
        } else if constexpr (EPI == EPI_QK) {
          // cols [0,4096) -> q; [4096,6144) -> k. 128-multiple boundary.
          if (col < 4096) {
            ((bf16*)Cout)[(size_t)row * 4096 + col] = __float2bfloat16(v);
          } else {
            ((bf16*)C2)[(size_t)row * 2048 + (col - 4096)] =
                __float2bfloat16(v);
          }
        } else if constexpr (EPI == EPI_VSW) {
          // swapped V GEMM: row = kv-dim (kvh*256+d), col = token (b*2048+s).
          const int bb = col >> 11, s = col & 2047;
          ((bf16*)Cout)[(((size_t)((bb * 8 + (row >> 8)) * 256 + (row & 255)))
                         << 11) + s] = __float2bfloat16(v);
        } else {  // EPI_GELUMUL
          const float g = __bfloat162float(aux[(size_t)row * Ndim + col]);
          const float u = 0.7978845608028654f * (g + 0.044715f * g * g * g);
          const float gl = 0.5f * g * (1.f + tanhf(u));
          ((bf16*)Cout)[(size_t)row * Ndim + col] = __float2bfloat16(gl * v);
        }
      }
    }
  }
  (void)aux; (void)C2;
}

// ---------------------------------------------------------------------------
// RMSNorm of input hidden -> bf16
// ---------------------------------------------------------------------------
__global__ __launch_bounds__(256) void rmsnorm_in(
    const float* __restrict__ x, const float* __restrict__ w,
    bf16* __restrict__ out) {
  const int row = blockIdx.x, t = threadIdx.x;
  const float4* xr = (const float4*)(x + (size_t)row * HID);
  float4 v[4];
  float ss = 0.f;
  #pragma unroll
  for (int j = 0; j < 4; j++) {
    const int idx = t + 256 * j;
    if (idx < HID / 4) {
      v[j] = xr[idx];
      ss += v[j].x * v[j].x + v[j].y * v[j].y + v[j].z * v[j].z + v[j].w * v[j].w;
    }
  }
  ss = block_reduce_sum(ss);
  const float sc = rsqrtf(ss * (1.f / HID) + EPSF);
  const float4* w4 = (const float4*)w;
  bf16* orow = out + (size_t)row * HID;
  #pragma unroll
  for (int j = 0; j < 4; j++) {
    const int idx = t + 256 * j;
    if (idx < HID / 4) {
      const float4 wv = w4[idx];
      ushort4 o;
      o.x = f2bu(v[j].x * sc * (1.f + wv.x));
      o.y = f2bu(v[j].y * sc * (1.f + wv.y));
      o.z = f2bu(v[j].z * sc * (1.f + wv.z));
      o.w = f2bu(v[j].w * sc * (1.f + wv.w));
      *(ushort4*)(orow + idx * 4) = o;
    }
  }
}

// ---------------------------------------------------------------------------
// RoPE in-place on q (16 heads) and k (8 heads), bf16.
// ---------------------------------------------------------------------------
__global__ __launch_bounds__(128) void rope_kernel(
    bf16* __restrict__ q, bf16* __restrict__ k,
    const float* __restrict__ cosb, const float* __restrict__ sinb) {
  const int tok = blockIdx.x;
  const int hs = blockIdx.y;
  const int d = threadIdx.x;
  const int s = tok & (SEQ - 1);
  bf16* ptr = (hs < NHEADS)
                  ? q + (size_t)tok * QOUT + hs * HDIM
                  : k + (size_t)tok * KOUT + (hs - NHEADS) * HDIM;
  const float c = cosb[s * HDIM + d];
  const float sn = sinb[s * HDIM + d];
  const float x0 = __bfloat162float(ptr[d]);
  const float x1 = __bfloat162float(ptr[d + 128]);
  ptr[d] = __float2bfloat16(x0 * c - x1 * sn);
  ptr[d + 128] = __float2bfloat16(x1 * c + x0 * sn);
}

// ---------------------------------------------------------------------------
// Flash attention, sliding window 1024, softcap 50, fixed-base softmax.
// ---------------------------------------------------------------------------
__global__ __launch_bounds__(256) void attn_kernel(
    const bf16* __restrict__ q, const bf16* __restrict__ k,
    const bf16* __restrict__ vt, bf16* __restrict__ out) {
  __shared__ __align__(16) bf16 plds[4][16 * 32];

  const int qt = blockIdx.x, h = blockIdx.y, b = blockIdx.z;
  const int w = threadIdx.x >> 6, l = threadIdx.x & 63;
  const int kvh = h >> 1;
  const int qbase = qt * 64 + w * 16;
  const int lr = l & 15, lg = l >> 4, lk = lg * 8;

  bf16x8_t qf[8];
  const bf16* qrow = q + (size_t)(b * SEQ + qbase + lr) * QOUT + h * HDIM;
  #pragma unroll
  for (int c = 0; c < 8; c++) qf[c] = *(const bf16x8_t*)(qrow + c * 32 + lk);

  f32x4_t acc[16];
  #pragma unroll
  for (int i = 0; i < 16; i++) acc[i] = (f32x4_t){0.f, 0.f, 0.f, 0.f};
  float L[4] = {0.f, 0.f, 0.f, 0.f};

  const bf16* kp = k + (size_t)(b * SEQ) * KOUT + kvh * HDIM;
  const bf16* vp = vt + (size_t)(b * NKVH + kvh) * HDIM * SEQ;
  bf16* pl = &plds[w][0];

  int kstart = qbase - 1023;
  if (kstart < 0) kstart = 0;
  kstart &= ~31;
  const int kend = qbase + 15;

  for (int kb = kstart; kb <= kend; kb += 32) {
    f32x4_t s0 = (f32x4_t){0.f, 0.f, 0.f, 0.f};
    f32x4_t s1 = (f32x4_t){0.f, 0.f, 0.f, 0.f};
    #pragma unroll
    for (int c = 0; c < 8; c++) {
      bf16x8_t k0 = *(const bf16x8_t*)(kp + (size_t)(kb + lr) * KOUT + c * 32 + lk);
      bf16x8_t k1 = *(const bf16x8_t*)(kp + (size_t)(kb + 16 + lr) * KOUT + c * 32 + lk);
      s0 = mfma16(qf[c], k0, s0);
      s1 = mfma16(qf[c], k1, s1);
    }
    float p[8];
    #pragma unroll
    for (int sub = 0; sub < 2; sub++) {
      const int j = kb + sub * 16 + lr;
      #pragma unroll
      for (int r = 0; r < 4; r++) {
        const int i = qbase + lg * 4 + r;
        float sc = (sub ? s1[r] : s0[r]) * 0.0625f;
        sc = 50.f * tanhf(sc * 0.02f);
        const bool ok = (j <= i) && (j > i - 1024);
        p[sub * 4 + r] = ok ? __expf(sc) : 0.f;
      }
    }
    #pragma unroll
    for (int r = 0; r < 4; r++) {
      float ps = p[r] + p[4 + r];
      ps += __shfl_xor(ps, 1, 64);
      ps += __shfl_xor(ps, 2, 64);
      ps += __shfl_xor(ps, 4, 64);
      ps += __shfl_xor(ps, 8, 64);
      L[r] += ps;
    }
    #pragma unroll
    for (int sub = 0; sub < 2; sub++)
      #pragma unroll
      for (int r = 0; r < 4; r++)
        pl[(lg * 4 + r) * 32 + sub * 16 + lr] = __float2bfloat16(p[sub * 4 + r]);
    asm volatile("s_waitcnt lgkmcnt(0)" ::: "memory");
    const bf16x8_t pa = *(const bf16x8_t*)(pl + lr * 32 + lk);
    #pragma unroll
    for (int dt = 0; dt < 16; dt++) {
      bf16x8_t bv = *(const bf16x8_t*)(vp + (size_t)(dt * 16 + lr) * SEQ + kb + lk);
      acc[dt] = mfma16(pa, bv, acc[dt]);
    }
  }

  float rL[4];
  #pragma unroll
  for (int r = 0; r < 4; r++) rL[r] = 1.f / L[r];
  #pragma unroll
  for (int dt = 0; dt < 16; dt++) {
    #pragma unroll
    for (int r = 0; r < 4; r++) {
      const int tok = b * SEQ + qbase + lg * 4 + r;
      out[(size_t)tok * QOUT + h * HDIM + dt * 16 + lr] =
          __float2bfloat16(acc[dt][r] * rL[r]);
    }
  }
}

// ---------------------------------------------------------------------------
// fuse1: h1 = hidden + rmsnorm(attn_proj, w_post); y = bf16(rmsnorm(h1, w_pre))
// ---------------------------------------------------------------------------
__global__ __launch_bounds__(256) void fuse_attn(
    const float* __restrict__ hidden, const float* __restrict__ ap,
    const float* __restrict__ w_post, const float* __restrict__ w_pre,
    float* __restrict__ h1, bf16* __restrict__ y) {
  const int row = blockIdx.x, t = threadIdx.x;
  const float4* ar = (const float4*)(ap + (size_t)row * HID);
  const float4* hr = (const float4*)(hidden + (size_t)row * HID);
  float4 a[4];
  float ss = 0.f;
  #pragma unroll
  for (int j = 0; j < 4; j++) {
    const int idx = t + 256 * j;
    if (idx < HID / 4) {
      a[j] = ar[idx];
      ss += a[j].x * a[j].x + a[j].y * a[j].y + a[j].z * a[j].z + a[j].w * a[j].w;
    }
  }
  ss = block_reduce_sum(ss);
  const float sc = rsqrtf(ss * (1.f / HID) + EPSF);
  const float4* wpo = (const float4*)w_post;
  float4* h1r = (float4*)(h1 + (size_t)row * HID);
  float4 hv[4];
  float ss2 = 0.f;
  #pragma unroll
  for (int j = 0; j < 4; j++) {
    const int idx = t + 256 * j;
    if (idx < HID / 4) {
      const float4 wv = wpo[idx];
      const float4 x = hr[idx];
      hv[j].x = x.x + a[j].x * sc * (1.f + wv.x);
      hv[j].y = x.y + a[j].y * sc * (1.f + wv.y);
      hv[j].z = x.z + a[j].z * sc * (1.f + wv.z);
      hv[j].w = x.w + a[j].w * sc * (1.f + wv.w);
      ss2 += hv[j].x * hv[j].x + hv[j].y * hv[j].y + hv[j].z * hv[j].z + hv[j].w * hv[j].w;
      h1r[idx] = hv[j];
    }
  }
  ss2 = block_reduce_sum(ss2);
  const float sc2 = rsqrtf(ss2 * (1.f / HID) + EPSF);
  const float4* wpr = (const float4*)w_pre;
  bf16* yr = y + (size_t)row * HID;
  #pragma unroll
  for (int j = 0; j < 4; j++) {
    const int idx = t + 256 * j;
    if (idx < HID / 4) {
      const float4 wv = wpr[idx];
      ushort4 o;
      o.x = f2bu(hv[j].x * sc2 * (1.f + wv.x));
      o.y = f2bu(hv[j].y * sc2 * (1.f + wv.y));
      o.z = f2bu(hv[j].z * sc2 * (1.f + wv.z));
      o.w = f2bu(hv[j].w * sc2 * (1.f + wv.w));
      *(ushort4*)(yr + idx * 4) = o;
    }
  }
}

// ---------------------------------------------------------------------------
// fuse2: out = h1 + rmsnorm(mlp, w_post_ff)
// ---------------------------------------------------------------------------
__global__ __launch_bounds__(256) void fuse_out(
    const float* __restrict__ h1, const float* __restrict__ mlp,
    const float* __restrict__ w, float* __restrict__ out) {
  const int row = blockIdx.x, t = threadIdx.x;
  const float4* mr = (const float4*)(mlp + (size_t)row * HID);
  float4 m[4];
  float ss = 0.f;
  #pragma unroll
  for (int j = 0; j < 4; j++) {
    const int idx = t + 256 * j;
    if (idx < HID / 4) {
      m[j] = mr[idx];
      ss += m[j].x * m[j].x + m[j].y * m[j].y + m[j].z * m[j].z + m[j].w * m[j].w;
    }
  }
  ss = block_reduce_sum(ss);
  const float sc = rsqrtf(ss * (1.f / HID) + EPSF);
  const float4* hr = (const float4*)(h1 + (size_t)row * HID);
  const float4* w4 = (const float4*)w;
  float4* orow = (float4*)(out + (size_t)row * HID);
  #pragma unroll
  for (int j = 0; j < 4; j++) {
    const int idx = t + 256 * j;
    if (idx < HID / 4) {
      const float4 wv = w4[idx];
      const float4 x = hr[idx];
      float4 o;
      o.x = x.x + m[j].x * sc * (1.f + wv.x);
      o.y = x.y + m[j].y * sc * (1.f + wv.y);
      o.z = x.z + m[j].z * sc * (1.f + wv.z);
      o.w = x.w + m[j].w * sc * (1.f + wv.w);
      orow[idx] = o;
    }
  }
}

// ---------------------------------------------------------------------------
extern "C" void kernel_launch(void* const* d_in, const int* in_sizes, int n_in,
                              void* d_out, int out_size, void* d_ws,
                              size_t ws_size, hipStream_t stream) {
  const float* hidden = (const float*)d_in[0];
  const float* cosb = (const float*)d_in[1];
  const float* sinb = (const float*)d_in[2];
  const float* Wq = (const float*)d_in[3];
  const float* Wk = (const float*)d_in[4];
  const float* Wv = (const float*)d_in[5];
  const float* Wo = (const float*)d_in[6];
  const float* Wgate = (const float*)d_in[7];
  const float* Wup = (const float*)d_in[8];
  const float* Wdown = (const float*)d_in[9];
  const float* w_in = (const float*)d_in[10];
  const float* w_post_attn = (const float*)d_in[11];
  const float* w_pre_ff = (const float*)d_in[12];
  const float* w_post_ff = (const float*)d_in[13];
  float* out = (float*)d_out;

  (void)in_sizes; (void)n_in; (void)out_size; (void)ws_size;

  const size_t WB = 102760448;  // 14336*3584*2 — bf16 weight scratch
  char* ws = (char*)d_ws;
  bf16* wbuf = (bf16*)ws;
  char* ab = ws + WB;

  bf16* xn = (bf16*)(ab);
  bf16* q = (bf16*)(ab + 29360128);
  float* attn_proj = (float*)(ab);
  float* mlp = (float*)(ab);
  bf16* kbuf = (bf16*)(ab + 62914560);
  bf16* vt = (bf16*)(ab + 62914560 + 16777216);
  bf16* attn_out = (bf16*)(ab + 62914560 + 33554432);
  float* h1 = (float*)(ab + 62914560);
  bf16* y = (bf16*)(ab + 130023424);
  bf16* gate = (bf16*)(ab + 159383552);

  rmsnorm_in<<<MTOK, 256, 0, stream>>>(hidden, w_in, xn);

  // wbuf rows [0,4096)=Wq, [4096,6144)=Wk, [6144,8192)=Wv
  cvt_w<<<4096, 256, 0, stream>>>(Wq, wbuf, QOUT * HID);
  cvt_w<<<2048, 256, 0, stream>>>(Wk, wbuf + (size_t)QOUT * HID, KOUT * HID);
  cvt_w<<<2048, 256, 0, stream>>>(Wv, wbuf + (size_t)(QOUT + KOUT) * HID,
                                  KOUT * HID);
  // QK: N=6144, M=4096 -> 48*32 blocks (mshift=5).
  gemm4w<EPI_QK><<<(6144 / 128) * 32, 256, 0, stream>>>(
      xn, wbuf, q, nullptr, kbuf, 6144, HID, 5);
  // V swapped: M=2048 (mshift=4), N=4096.
  gemm4w<EPI_VSW><<<(4096 / 128) * 16, 256, 0, stream>>>(
      wbuf + (size_t)(QOUT + KOUT) * HID, xn, vt, nullptr, nullptr,
      4096, HID, 4);
  rope_kernel<<<dim3(MTOK, NHEADS + NKVH), 128, 0, stream>>>(q, kbuf, cosb, sinb);
  attn_kernel<<<dim3(SEQ / 64, NHEADS, NBATCH), 256, 0, stream>>>(
      q, kbuf, vt, attn_out);
  cvt_w<<<4096, 256, 0, stream>>>(Wo, wbuf, HID * QOUT);
  gemm4w<EPI_F32><<<(HID / 128) * 32, 256, 0, stream>>>(
      attn_out, wbuf, attn_proj, nullptr, nullptr, HID, QOUT, 5);
  fuse_attn<<<MTOK, 256, 0, stream>>>(hidden, attn_proj, w_post_attn,
                                      w_pre_ff, h1, y);
  cvt_w<<<4096, 256, 0, stream>>>(Wgate, wbuf, INTERD * HID);
  gemm4w<EPI_BF16><<<(INTERD / 128) * 32, 256, 0, stream>>>(
      y, wbuf, gate, nullptr, nullptr, INTERD, HID, 5);
  cvt_w<<<4096, 256, 0, stream>>>(Wup, wbuf, INTERD * HID);
  gemm4w<EPI_GELUMUL><<<(INTERD / 128) * 32, 256, 0, stream>>>(
      y, wbuf, gate, gate, nullptr, INTERD, HID, 5);
  cvt_w<<<4096, 256, 0, stream>>>(Wdown, wbuf, INTERD * HID);
  gemm4w<EPI_F32><<<(HID / 128) * 32, 256, 0, stream>>>(
      gate, wbuf, mlp, nullptr, nullptr, HID, INTERD, 5);

  fuse_out<<<MTOK, 256, 0, stream>>>(h1, mlp, w_post_ff, out);
}